// Round 1
// baseline (277.813 us; speedup 1.0000x reference)
//
#include <hip/hip_runtime.h>
#include <hip/hip_bf16.h>
#include <math.h>

typedef short short8 __attribute__((ext_vector_type(8)));
typedef float floatx4 __attribute__((ext_vector_type(4)));

#define NB 4096
#define DD 128
static constexpr float EPSF = 1e-8f;
static constexpr float TEMP = 11.313708498984760390f; // sqrt(128)

// ---------------- zero S ----------------
__global__ void zero_kernel(float* __restrict__ S) {
    int i = blockIdx.x * blockDim.x + threadIdx.x;
    if (i < NB) S[i] = 0.0f;
}

// ---------------- projection + metric-normalize ----------------
// q = x @ W^T + b; s = ||q||^2; fro = sqrt(s^2/D^2 + 2s/D + D);
// qnorm = sqrt((s^2/D + s)/(fro+EPS)); qn = q/(qnorm+EPS)  -> bf16
// rq = sum(qn_bf16^2) (consistent with the dot operands)
#define RPB 8
__global__ __launch_bounds__(128) void proj_kernel(
    const float* __restrict__ qp, const float* __restrict__ kp,
    const float* __restrict__ Wq, const float* __restrict__ bq,
    const float* __restrict__ Wk, const float* __restrict__ bk,
    __hip_bfloat16* __restrict__ qn, __hip_bfloat16* __restrict__ kn,
    float* __restrict__ rq, float* __restrict__ rk)
{
    int t = threadIdx.x;
    int lane = t & 63, w = t >> 6;
    int grp = blockIdx.x;            // 0..1023; 512 blocks per matrix
    int which = grp >> 9;
    int r0 = (grp & 511) * RPB;

    const float* x    = which ? kp : qp;
    const float* W    = which ? Wk : Wq;
    const float* bias = which ? bk : bq;
    __hip_bfloat16* outv = which ? kn : qn;
    float* outr = which ? rk : rq;

    __shared__ float xs[RPB][DD];
    __shared__ float part[2][RPB];
    __shared__ float part2[2][RPB];

    #pragma unroll
    for (int r = 0; r < RPB; ++r) xs[r][t] = x[(r0 + r) * DD + t];

    // W row t held in registers, reused across RPB rows
    float4 wreg[32];
    const float4* W4 = (const float4*)(W + t * DD);
    #pragma unroll
    for (int i = 0; i < 32; ++i) wreg[i] = W4[i];
    __syncthreads();

    float accv[RPB];
    float bv = bias[t];
    #pragma unroll
    for (int r = 0; r < RPB; ++r) {
        float a = bv;
        #pragma unroll
        for (int i = 0; i < 32; ++i) {
            a = fmaf(xs[r][4*i+0], wreg[i].x, a);
            a = fmaf(xs[r][4*i+1], wreg[i].y, a);
            a = fmaf(xs[r][4*i+2], wreg[i].z, a);
            a = fmaf(xs[r][4*i+3], wreg[i].w, a);
        }
        accv[r] = a;
    }

    // s[r] = sum over 128 threads of acc^2 (wave shuffle + 2-wave combine)
    #pragma unroll
    for (int r = 0; r < RPB; ++r) {
        float v = accv[r] * accv[r];
        v += __shfl_xor(v, 1);  v += __shfl_xor(v, 2);  v += __shfl_xor(v, 4);
        v += __shfl_xor(v, 8);  v += __shfl_xor(v, 16); v += __shfl_xor(v, 32);
        if (lane == 0) part[w][r] = v;
    }
    __syncthreads();

    float nf[RPB];
    #pragma unroll
    for (int r = 0; r < RPB; ++r) {
        float s = part[0][r] + part[1][r];
        float fro = sqrtf(s*s*(1.0f/16384.0f) + s*(1.0f/64.0f) + 128.0f);
        float qnorm = sqrtf((s*s*(1.0f/128.0f) + s) / (fro + EPSF));
        nf[r] = 1.0f / (qnorm + EPSF);
    }

    #pragma unroll
    for (int r = 0; r < RPB; ++r) {
        float v = accv[r] * nf[r];
        __hip_bfloat16 vb = __float2bfloat16(v);
        float vf = __bfloat162float(vb);
        outv[(r0 + r) * DD + t] = vb;
        float u = vf * vf;
        u += __shfl_xor(u, 1);  u += __shfl_xor(u, 2);  u += __shfl_xor(u, 4);
        u += __shfl_xor(u, 8);  u += __shfl_xor(u, 16); u += __shfl_xor(u, 32);
        if (lane == 0) part2[w][r] = u;
    }
    __syncthreads();
    if (t < RPB) outr[r0 + t] = part2[0][t] + part2[1][t];
}

// ---------------- scores: G = qn·kn^T (bf16 MFMA), exp, row partial sums ----
// Per wave: 64x64 output (4x4 tiles of 16x16x32 MFMA). Block 256 thr = 4 waves
// in 2x2 -> 128x128 per block. Fragments loaded straight from global (L2-hot).
// A-frag: A[m=lane&15][k=quad*8+j]; B-frag: B[n=lane&15][k=quad*8+j] (NT GEMM).
// C/D: col=lane&15, row=quad*4+reg.
__global__ __launch_bounds__(256) void scores_kernel(
    const __hip_bfloat16* __restrict__ qn, const __hip_bfloat16* __restrict__ kn,
    const float* __restrict__ rq, const float* __restrict__ rk,
    float* __restrict__ P, float* __restrict__ S)
{
    int lane = threadIdx.x & 63;
    int wid  = threadIdx.x >> 6;
    int m    = lane & 15;
    int quad = lane >> 4;

    int row0 = blockIdx.y * 128 + (wid >> 1) * 64;
    int col0 = blockIdx.x * 128 + (wid & 1) * 64;

    const short* qs = (const short*)qn;
    const short* kks = (const short*)kn;

    floatx4 acc[4][4];
    #pragma unroll
    for (int i = 0; i < 4; ++i)
        #pragma unroll
        for (int j = 0; j < 4; ++j)
            acc[i][j] = (floatx4){0.f, 0.f, 0.f, 0.f};

    #pragma unroll
    for (int ksx = 0; ksx < 4; ++ksx) {
        int koff = ksx * 32 + quad * 8;
        short8 af[4], bfr[4];
        #pragma unroll
        for (int rt = 0; rt < 4; ++rt)
            af[rt] = *(const short8*)(qs + (row0 + rt*16 + m) * DD + koff);
        #pragma unroll
        for (int ct = 0; ct < 4; ++ct)
            bfr[ct] = *(const short8*)(kks + (col0 + ct*16 + m) * DD + koff);
        #pragma unroll
        for (int rt = 0; rt < 4; ++rt)
            #pragma unroll
            for (int ct = 0; ct < 4; ++ct)
                acc[rt][ct] = __builtin_amdgcn_mfma_f32_16x16x32_bf16(
                    af[rt], bfr[ct], acc[rt][ct], 0, 0, 0);
    }

    // epilogue: d2 = rq[i] + rk[j] - 2g; e = exp(T/(1+sqrt(d2)))
    float ps[4][4]; // [rt][r] partial row sums over this wave's 64 cols
    #pragma unroll
    for (int rt = 0; rt < 4; ++rt)
        #pragma unroll
        for (int r = 0; r < 4; ++r) ps[rt][r] = 0.0f;

    #pragma unroll
    for (int rt = 0; rt < 4; ++rt) {
        #pragma unroll
        for (int r = 0; r < 4; ++r) {
            int row = row0 + rt*16 + quad*4 + r;
            float rqv = rq[row];
            #pragma unroll
            for (int ct = 0; ct < 4; ++ct) {
                int col = col0 + ct*16 + m;
                float g  = acc[rt][ct][r];
                float d2 = rqv + rk[col] - 2.0f * g;
                float d  = d2 > 0.0f ? sqrtf(d2) : 0.0f;
                float e  = __expf(TEMP / (1.0f + d));
                P[(long)row * NB + col] = e;
                ps[rt][r] += e;
            }
        }
    }

    // reduce across the 16 lanes sharing a row (lane&15 = col), then atomicAdd
    #pragma unroll
    for (int rt = 0; rt < 4; ++rt) {
        #pragma unroll
        for (int r = 0; r < 4; ++r) {
            float v = ps[rt][r];
            v += __shfl_xor(v, 1);
            v += __shfl_xor(v, 2);
            v += __shfl_xor(v, 4);
            v += __shfl_xor(v, 8);
            if (m == 0)
                atomicAdd(&S[row0 + rt*16 + quad*4 + r], v);
        }
    }
}

// ---------------- normalize: out = P / S[row] ----------------
__global__ __launch_bounds__(256) void norm_kernel(
    float* __restrict__ P, const float* __restrict__ S)
{
    float4* P4 = (float4*)P;
    const long total = (long)NB * NB / 4;          // 4,194,304 float4
    long stride = (long)gridDim.x * blockDim.x;
    for (long i = (long)blockIdx.x * blockDim.x + threadIdx.x; i < total; i += stride) {
        int row = (int)(i >> 10);                  // 1024 float4 per row
        float inv = 1.0f / S[row];
        float4 v = P4[i];
        v.x *= inv; v.y *= inv; v.z *= inv; v.w *= inv;
        P4[i] = v;
    }
}

extern "C" void kernel_launch(void* const* d_in, const int* in_sizes, int n_in,
                              void* d_out, int out_size, void* d_ws, size_t ws_size,
                              hipStream_t stream) {
    const float* qp = (const float*)d_in[0];
    const float* kp = (const float*)d_in[1];
    const float* Wq = (const float*)d_in[2];
    const float* bq = (const float*)d_in[3];
    const float* Wk = (const float*)d_in[4];
    const float* bk = (const float*)d_in[5];
    float* P = (float*)d_out;

    char* ws = (char*)d_ws;
    __hip_bfloat16* qn = (__hip_bfloat16*)ws;                         // 1 MB
    __hip_bfloat16* kn = (__hip_bfloat16*)(ws + (size_t)NB*DD*2);     // 1 MB
    float* rq = (float*)(ws + (size_t)NB*DD*4);                       // 16 KB
    float* rk = (float*)(ws + (size_t)NB*DD*4 + (size_t)NB*4);        // 16 KB
    float* S  = (float*)(ws + (size_t)NB*DD*4 + (size_t)2*NB*4);      // 16 KB

    hipLaunchKernelGGL(zero_kernel, dim3(16), dim3(256), 0, stream, S);
    hipLaunchKernelGGL(proj_kernel, dim3(1024), dim3(128), 0, stream,
                       qp, kp, Wq, bq, Wk, bk, qn, kn, rq, rk);
    hipLaunchKernelGGL(scores_kernel, dim3(32, 32), dim3(256), 0, stream,
                       qn, kn, rq, rk, P, S);
    hipLaunchKernelGGL(norm_kernel, dim3(8192), dim3(256), 0, stream, P, S);
}

// Round 2
// 163.693 us; speedup vs baseline: 1.6972x; 1.6972x over previous
//
#include <hip/hip_runtime.h>
#include <hip/hip_bf16.h>
#include <math.h>

typedef short short8 __attribute__((ext_vector_type(8)));
typedef float floatx4 __attribute__((ext_vector_type(4)));

#define NB 4096
#define DD 128
static constexpr float EPSF = 1e-8f;
static constexpr float TEMP = 11.313708498984760390f; // sqrt(128)

static __device__ __forceinline__ short f2bf(float f) {
    __hip_bfloat16 h = __float2bfloat16(f);
    union { __hip_bfloat16 h; short s; } u; u.h = h; return u.s;
}
static __device__ __forceinline__ float bf2f(short s) {
    union { __hip_bfloat16 h; short s; } u; u.s = s;
    return __bfloat162float(u.h);
}

// Pack 8 consecutive fp32 -> bf16x8 fragment
static __device__ __forceinline__ short8 load_cvt8(const float* __restrict__ p) {
    float4 a = *(const float4*)p;
    float4 b = *(const float4*)(p + 4);
    short8 o;
    o[0] = f2bf(a.x); o[1] = f2bf(a.y); o[2] = f2bf(a.z); o[3] = f2bf(a.w);
    o[4] = f2bf(b.x); o[5] = f2bf(b.y); o[6] = f2bf(b.z); o[7] = f2bf(b.w);
    return o;
}

// ---------------- projection + metric-normalize (MFMA, bf16) ----------------
// Block: 128 rows x 128 cols (full D), 4 waves in 2x2 of 64x64 wave tiles.
// q = x@W^T + b (bf16 MFMA, fp32 acc); s = ||q||^2 per row;
// fro = sqrt(s^2/D^2 + 2s/D + D); qnorm = sqrt((s^2/D + s)/(fro+EPS));
// qn = bf16(q/(qnorm+EPS)); rq = sum(qn_bf16^2). Also zeroes S (64 floats/blk).
__global__ __launch_bounds__(256) void proj_kernel(
    const float* __restrict__ qp, const float* __restrict__ kp,
    const float* __restrict__ Wq, const float* __restrict__ bq,
    const float* __restrict__ Wk, const float* __restrict__ bk,
    __hip_bfloat16* __restrict__ qn, __hip_bfloat16* __restrict__ kn,
    float* __restrict__ rq, float* __restrict__ rk, float* __restrict__ S)
{
    int t = threadIdx.x;
    int b = blockIdx.x;                 // 64 blocks: 32 per matrix
    if (t < 64) S[b * 64 + t] = 0.0f;   // fold in zeroing of the softmax sums

    int which = b >> 5;
    int row0 = (b & 31) * 128;
    const float* x    = which ? kp : qp;
    const float* W    = which ? Wk : Wq;
    const float* bias = which ? bk : bq;
    short* outv = which ? (short*)kn : (short*)qn;
    float* outr = which ? rk : rq;

    int lane = t & 63, wid = t >> 6;
    int m = lane & 15, quad = lane >> 4;
    int rowb = (wid >> 1) * 64;         // block-local wave row origin
    int colb = (wid & 1) * 64;          // wave col origin

    floatx4 acc[4][4];
    #pragma unroll
    for (int i = 0; i < 4; ++i)
        #pragma unroll
        for (int j = 0; j < 4; ++j)
            acc[i][j] = (floatx4){0.f, 0.f, 0.f, 0.f};

    #pragma unroll
    for (int ks = 0; ks < 4; ++ks) {
        int koff = ks * 32 + quad * 8;
        short8 af[4], bfr[4];
        #pragma unroll
        for (int rt = 0; rt < 4; ++rt)
            af[rt] = load_cvt8(x + (row0 + rowb + rt*16 + m) * DD + koff);
        #pragma unroll
        for (int ct = 0; ct < 4; ++ct)
            bfr[ct] = load_cvt8(W + (colb + ct*16 + m) * DD + koff);
        #pragma unroll
        for (int rt = 0; rt < 4; ++rt)
            #pragma unroll
            for (int ct = 0; ct < 4; ++ct)
                acc[rt][ct] = __builtin_amdgcn_mfma_f32_16x16x32_bf16(
                    af[rt], bfr[ct], acc[rt][ct], 0, 0, 0);
    }

    __shared__ float buf[4][64];
    __shared__ float nfb[128];

    float bv[4];
    #pragma unroll
    for (int ct = 0; ct < 4; ++ct) bv[ct] = bias[colb + ct*16 + m];

    // add bias, row-sum of squares (this wave's 64 cols), reduce over m-lanes
    #pragma unroll
    for (int rt = 0; rt < 4; ++rt) {
        #pragma unroll
        for (int r = 0; r < 4; ++r) {
            float p = 0.0f;
            #pragma unroll
            for (int ct = 0; ct < 4; ++ct) {
                float v = acc[rt][ct][r] + bv[ct];
                acc[rt][ct][r] = v;
                p = fmaf(v, v, p);
            }
            p += __shfl_xor(p, 1); p += __shfl_xor(p, 2);
            p += __shfl_xor(p, 4); p += __shfl_xor(p, 8);
            if (m == 0) buf[wid][rt*16 + quad*4 + r] = p;
        }
    }
    __syncthreads();
    if (t < 128) {
        int half = t >> 6, i = t & 63;
        float s = buf[half*2][i] + buf[half*2 + 1][i];
        float fro = sqrtf(s*s*(1.0f/16384.0f) + s*(1.0f/64.0f) + 128.0f);
        float qnorm = sqrtf((s*s*(1.0f/128.0f) + s) / (fro + EPSF));
        nfb[t] = 1.0f / (qnorm + EPSF);
    }
    __syncthreads();

    // scale, round to bf16, store, and row-sum of rounded squares
    #pragma unroll
    for (int rt = 0; rt < 4; ++rt) {
        #pragma unroll
        for (int r = 0; r < 4; ++r) {
            int lrow = rowb + rt*16 + quad*4 + r;   // block-local 0..127
            float nf = nfb[lrow];
            float u = 0.0f;
            #pragma unroll
            for (int ct = 0; ct < 4; ++ct) {
                float v = acc[rt][ct][r] * nf;
                short sb = f2bf(v);
                outv[(row0 + lrow) * DD + colb + ct*16 + m] = sb;
                float vf = bf2f(sb);
                u = fmaf(vf, vf, u);
            }
            u += __shfl_xor(u, 1); u += __shfl_xor(u, 2);
            u += __shfl_xor(u, 4); u += __shfl_xor(u, 8);
            if (m == 0) buf[wid][rt*16 + quad*4 + r] = u;
        }
    }
    __syncthreads();
    if (t < 128) {
        int half = t >> 6, i = t & 63;
        outr[row0 + t] = buf[half*2][i] + buf[half*2 + 1][i];
    }
}

// ---------------- score passes: G = qn·kn^T, e = exp(T/(1+dist)) ------------
// PASS 1: row sums of e -> atomicAdd S (no P store).
// PASS 2: identical GEMM (bitwise-same acc), write P = e / S[row].
template<int PASS>
__global__ __launch_bounds__(256) void score_pass(
    const __hip_bfloat16* __restrict__ qn, const __hip_bfloat16* __restrict__ kn,
    const float* __restrict__ rq, const float* __restrict__ rk,
    float* __restrict__ S, float* __restrict__ P)
{
    int lane = threadIdx.x & 63;
    int wid  = threadIdx.x >> 6;
    int m    = lane & 15;
    int quad = lane >> 4;

    int row0 = blockIdx.y * 128 + (wid >> 1) * 64;
    int col0 = blockIdx.x * 128 + (wid & 1) * 64;

    const short* qs  = (const short*)qn;
    const short* kks = (const short*)kn;

    __shared__ float sinv[128];
    if (PASS == 2) {
        if (threadIdx.x < 128)
            sinv[threadIdx.x] = 1.0f / (S[blockIdx.y * 128 + threadIdx.x] + EPSF);
        __syncthreads();
    }

    floatx4 acc[4][4];
    #pragma unroll
    for (int i = 0; i < 4; ++i)
        #pragma unroll
        for (int j = 0; j < 4; ++j)
            acc[i][j] = (floatx4){0.f, 0.f, 0.f, 0.f};

    #pragma unroll
    for (int ks = 0; ks < 4; ++ks) {
        int koff = ks * 32 + quad * 8;
        short8 af[4], bfr[4];
        #pragma unroll
        for (int rt = 0; rt < 4; ++rt)
            af[rt] = *(const short8*)(qs + (row0 + rt*16 + m) * DD + koff);
        #pragma unroll
        for (int ct = 0; ct < 4; ++ct)
            bfr[ct] = *(const short8*)(kks + (col0 + ct*16 + m) * DD + koff);
        #pragma unroll
        for (int rt = 0; rt < 4; ++rt)
            #pragma unroll
            for (int ct = 0; ct < 4; ++ct)
                acc[rt][ct] = __builtin_amdgcn_mfma_f32_16x16x32_bf16(
                    af[rt], bfr[ct], acc[rt][ct], 0, 0, 0);
    }

    #pragma unroll
    for (int rt = 0; rt < 4; ++rt) {
        #pragma unroll
        for (int r = 0; r < 4; ++r) {
            int row = row0 + rt*16 + quad*4 + r;
            float rqv = rq[row];
            float es = 0.0f;
            float inv = (PASS == 2) ? sinv[row - blockIdx.y * 128] : 0.0f;
            #pragma unroll
            for (int ct = 0; ct < 4; ++ct) {
                int col = col0 + ct*16 + m;
                float g  = acc[rt][ct][r];
                float d2 = rqv + rk[col] - 2.0f * g;
                float d  = d2 > 0.0f ? sqrtf(d2) : 0.0f;
                float e  = __expf(TEMP / (1.0f + d));
                if (PASS == 1) es += e;
                else P[(long)row * NB + col] = e * inv;
            }
            if (PASS == 1) {
                es += __shfl_xor(es, 1); es += __shfl_xor(es, 2);
                es += __shfl_xor(es, 4); es += __shfl_xor(es, 8);
                if (m == 0) atomicAdd(&S[row], es);
            }
        }
    }
}

extern "C" void kernel_launch(void* const* d_in, const int* in_sizes, int n_in,
                              void* d_out, int out_size, void* d_ws, size_t ws_size,
                              hipStream_t stream) {
    const float* qp = (const float*)d_in[0];
    const float* kp = (const float*)d_in[1];
    const float* Wq = (const float*)d_in[2];
    const float* bq = (const float*)d_in[3];
    const float* Wk = (const float*)d_in[4];
    const float* bk = (const float*)d_in[5];
    float* P = (float*)d_out;

    char* ws = (char*)d_ws;
    __hip_bfloat16* qn = (__hip_bfloat16*)ws;                         // 1 MB
    __hip_bfloat16* kn = (__hip_bfloat16*)(ws + (size_t)NB*DD*2);     // 1 MB
    float* rq = (float*)(ws + (size_t)NB*DD*4);                       // 16 KB
    float* rk = (float*)(ws + (size_t)NB*DD*4 + (size_t)NB*4);        // 16 KB
    float* S  = (float*)(ws + (size_t)NB*DD*4 + (size_t)2*NB*4);      // 16 KB

    hipLaunchKernelGGL(proj_kernel, dim3(64), dim3(256), 0, stream,
                       qp, kp, Wq, bq, Wk, bk, qn, kn, rq, rk, S);
    hipLaunchKernelGGL((score_pass<1>), dim3(32, 32), dim3(256), 0, stream,
                       qn, kn, rq, rk, S, P);
    hipLaunchKernelGGL((score_pass<2>), dim3(32, 32), dim3(256), 0, stream,
                       qn, kn, rq, rk, S, P);
}

// Round 4
// 155.658 us; speedup vs baseline: 1.7848x; 1.0516x over previous
//
#include <hip/hip_runtime.h>
#include <hip/hip_bf16.h>
#include <math.h>

typedef short short8 __attribute__((ext_vector_type(8)));
typedef float floatx4 __attribute__((ext_vector_type(4)));

#define NB 4096
#define DD 128
static constexpr float EPSF = 1e-8f;
static constexpr float TEMP = 11.313708498984760390f; // sqrt(128)

static __device__ __forceinline__ short f2bf(float f) {
    __hip_bfloat16 h = __float2bfloat16(f);
    union { __hip_bfloat16 h; short s; } u; u.h = h; return u.s;
}
static __device__ __forceinline__ float bf2f(short s) {
    union { __hip_bfloat16 h; short s; } u; u.s = s;
    return __bfloat162float(u.h);
}

// Pack 8 consecutive fp32 -> bf16x8 fragment
static __device__ __forceinline__ short8 load_cvt8(const float* __restrict__ p) {
    float4 a = *(const float4*)p;
    float4 b = *(const float4*)(p + 4);
    short8 o;
    o[0] = f2bf(a.x); o[1] = f2bf(a.y); o[2] = f2bf(a.z); o[3] = f2bf(a.w);
    o[4] = f2bf(b.x); o[5] = f2bf(b.y); o[6] = f2bf(b.z); o[7] = f2bf(b.w);
    return o;
}

// ---------------- projection + metric-normalize (MFMA, bf16) ----------------
// 256 blocks (one per CU): 32 rows x 128 cols each. 4 waves, each 32x32
// (2x2 tiles of 16x16x32). Also zeroes S (16 floats/block).
__global__ __launch_bounds__(256) void proj_kernel(
    const float* __restrict__ qp, const float* __restrict__ kp,
    const float* __restrict__ Wq, const float* __restrict__ bq,
    const float* __restrict__ Wk, const float* __restrict__ bk,
    __hip_bfloat16* __restrict__ qn, __hip_bfloat16* __restrict__ kn,
    float* __restrict__ rq, float* __restrict__ rk, float* __restrict__ S)
{
    int t = threadIdx.x;
    int b = blockIdx.x;                 // 0..255; 128 per matrix
    if (t < 16) S[b * 16 + t] = 0.0f;   // 256*16 = 4096

    int which = b >> 7;
    int row0 = (b & 127) * 32;
    const float* x    = which ? kp : qp;
    const float* W    = which ? Wk : Wq;
    const float* bias = which ? bk : bq;
    short* outv = which ? (short*)kn : (short*)qn;
    float* outr = which ? rk : rq;

    int lane = t & 63, wid = t >> 6;
    int m = lane & 15, quad = lane >> 4;
    int colb = wid * 32;                // wave col origin (4 waves x 32 cols)

    floatx4 acc[2][2];
    #pragma unroll
    for (int i = 0; i < 2; ++i)
        #pragma unroll
        for (int j = 0; j < 2; ++j)
            acc[i][j] = (floatx4){0.f, 0.f, 0.f, 0.f};

    #pragma unroll
    for (int ks = 0; ks < 4; ++ks) {
        int koff = ks * 32 + quad * 8;
        short8 af[2], bfr[2];
        #pragma unroll
        for (int rt = 0; rt < 2; ++rt)
            af[rt] = load_cvt8(x + (row0 + rt*16 + m) * DD + koff);
        #pragma unroll
        for (int ct = 0; ct < 2; ++ct)
            bfr[ct] = load_cvt8(W + (colb + ct*16 + m) * DD + koff);
        #pragma unroll
        for (int rt = 0; rt < 2; ++rt)
            #pragma unroll
            for (int ct = 0; ct < 2; ++ct)
                acc[rt][ct] = __builtin_amdgcn_mfma_f32_16x16x32_bf16(
                    af[rt], bfr[ct], acc[rt][ct], 0, 0, 0);
    }

    __shared__ float buf[4][32];
    __shared__ float nfb[32];

    float bv[2];
    #pragma unroll
    for (int ct = 0; ct < 2; ++ct) bv[ct] = bias[colb + ct*16 + m];

    // add bias; per-row sum of squares (this wave's 32 cols), reduce over m
    #pragma unroll
    for (int rt = 0; rt < 2; ++rt) {
        #pragma unroll
        for (int r = 0; r < 4; ++r) {
            float p = 0.0f;
            #pragma unroll
            for (int ct = 0; ct < 2; ++ct) {
                float v = acc[rt][ct][r] + bv[ct];
                acc[rt][ct][r] = v;
                p = fmaf(v, v, p);
            }
            p += __shfl_xor(p, 1); p += __shfl_xor(p, 2);
            p += __shfl_xor(p, 4); p += __shfl_xor(p, 8);
            if (m == 0) buf[wid][rt*16 + quad*4 + r] = p;
        }
    }
    __syncthreads();
    if (t < 32) {
        float s = buf[0][t] + buf[1][t] + buf[2][t] + buf[3][t];
        float fro = sqrtf(s*s*(1.0f/16384.0f) + s*(1.0f/64.0f) + 128.0f);
        float qnorm = sqrtf((s*s*(1.0f/128.0f) + s) / (fro + EPSF));
        nfb[t] = 1.0f / (qnorm + EPSF);
    }
    __syncthreads();

    // scale, round to bf16, store; row-sum of rounded squares
    #pragma unroll
    for (int rt = 0; rt < 2; ++rt) {
        #pragma unroll
        for (int r = 0; r < 4; ++r) {
            int lrow = rt*16 + quad*4 + r;      // block-local 0..31
            float nf = nfb[lrow];
            float u = 0.0f;
            #pragma unroll
            for (int ct = 0; ct < 2; ++ct) {
                float v = acc[rt][ct][r] * nf;
                short sb = f2bf(v);
                outv[(row0 + lrow) * DD + colb + ct*16 + m] = sb;
                float vf = bf2f(sb);
                u = fmaf(vf, vf, u);
            }
            u += __shfl_xor(u, 1); u += __shfl_xor(u, 2);
            u += __shfl_xor(u, 4); u += __shfl_xor(u, 8);
            if (m == 0) buf[wid][lrow] = u;
        }
    }
    __syncthreads();
    if (t < 32)
        outr[row0 + t] = buf[0][t] + buf[1][t] + buf[2][t] + buf[3][t];
}

// ---------------- score passes: G = qn·kn^T, e = exp(T/(1+dist)) ------------
// PASS 1: row sums of e -> atomicAdd S (no P store).
// PASS 2: identical GEMM + epilogue (bitwise-same e), write P = e / S[row].
// Epilogue uses HW-rate sqrt/rcp (1-ulp) — identical sequence both passes.
template<int PASS>
__global__ __launch_bounds__(256) void score_pass(
    const __hip_bfloat16* __restrict__ qn, const __hip_bfloat16* __restrict__ kn,
    const float* __restrict__ rq, const float* __restrict__ rk,
    float* __restrict__ S, float* __restrict__ P)
{
    int lane = threadIdx.x & 63;
    int wid  = threadIdx.x >> 6;
    int m    = lane & 15;
    int quad = lane >> 4;

    int row0 = blockIdx.y * 128 + (wid >> 1) * 64;
    int col0 = blockIdx.x * 128 + (wid & 1) * 64;

    const short* qs  = (const short*)qn;
    const short* kks = (const short*)kn;

    __shared__ float sinv[128];
    if (PASS == 2) {
        if (threadIdx.x < 128)
            sinv[threadIdx.x] =
                __builtin_amdgcn_rcpf(S[blockIdx.y * 128 + threadIdx.x] + EPSF);
        __syncthreads();
    }

    floatx4 acc[4][4];
    #pragma unroll
    for (int i = 0; i < 4; ++i)
        #pragma unroll
        for (int j = 0; j < 4; ++j)
            acc[i][j] = (floatx4){0.f, 0.f, 0.f, 0.f};

    #pragma unroll
    for (int ks = 0; ks < 4; ++ks) {
        int koff = ks * 32 + quad * 8;
        short8 af[4], bfr[4];
        #pragma unroll
        for (int rt = 0; rt < 4; ++rt)
            af[rt] = *(const short8*)(qs + (row0 + rt*16 + m) * DD + koff);
        #pragma unroll
        for (int ct = 0; ct < 4; ++ct)
            bfr[ct] = *(const short8*)(kks + (col0 + ct*16 + m) * DD + koff);
        #pragma unroll
        for (int rt = 0; rt < 4; ++rt)
            #pragma unroll
            for (int ct = 0; ct < 4; ++ct)
                acc[rt][ct] = __builtin_amdgcn_mfma_f32_16x16x32_bf16(
                    af[rt], bfr[ct], acc[rt][ct], 0, 0, 0);
    }

    float rkv[4];
    #pragma unroll
    for (int ct = 0; ct < 4; ++ct) rkv[ct] = rk[col0 + ct*16 + m];

    #pragma unroll
    for (int rt = 0; rt < 4; ++rt) {
        #pragma unroll
        for (int r = 0; r < 4; ++r) {
            int row = row0 + rt*16 + quad*4 + r;
            float rqv = rq[row];
            float es = 0.0f;
            float inv = (PASS == 2) ? sinv[row - blockIdx.y * 128] : 0.0f;
            #pragma unroll
            for (int ct = 0; ct < 4; ++ct) {
                int col = col0 + ct*16 + m;
                float g  = acc[rt][ct][r];
                float d2 = fmaf(-2.0f, g, rqv + rkv[ct]);
                float d  = d2 > 0.0f ? __builtin_amdgcn_sqrtf(d2) : 0.0f;
                float e  = __expf(TEMP * __builtin_amdgcn_rcpf(1.0f + d));
                if (PASS == 1) es += e;
                else __builtin_nontemporal_store(e * inv, &P[(long)row * NB + col]);
            }
            if (PASS == 1) {
                es += __shfl_xor(es, 1); es += __shfl_xor(es, 2);
                es += __shfl_xor(es, 4); es += __shfl_xor(es, 8);
                if (m == 0) atomicAdd(&S[row], es);
            }
        }
    }
}

extern "C" void kernel_launch(void* const* d_in, const int* in_sizes, int n_in,
                              void* d_out, int out_size, void* d_ws, size_t ws_size,
                              hipStream_t stream) {
    const float* qp = (const float*)d_in[0];
    const float* kp = (const float*)d_in[1];
    const float* Wq = (const float*)d_in[2];
    const float* bq = (const float*)d_in[3];
    const float* Wk = (const float*)d_in[4];
    const float* bk = (const float*)d_in[5];
    float* P = (float*)d_out;

    char* ws = (char*)d_ws;
    __hip_bfloat16* qn = (__hip_bfloat16*)ws;                         // 1 MB
    __hip_bfloat16* kn = (__hip_bfloat16*)(ws + (size_t)NB*DD*2);     // 1 MB
    float* rq = (float*)(ws + (size_t)NB*DD*4);                       // 16 KB
    float* rk = (float*)(ws + (size_t)NB*DD*4 + (size_t)NB*4);        // 16 KB
    float* S  = (float*)(ws + (size_t)NB*DD*4 + (size_t)2*NB*4);      // 16 KB

    hipLaunchKernelGGL(proj_kernel, dim3(256), dim3(256), 0, stream,
                       qp, kp, Wq, bq, Wk, bk, qn, kn, rq, rk, S);
    hipLaunchKernelGGL((score_pass<1>), dim3(32, 32), dim3(256), 0, stream,
                       qn, kn, rq, rk, S, P);
    hipLaunchKernelGGL((score_pass<2>), dim3(32, 32), dim3(256), 0, stream,
                       qn, kn, rq, rk, S, P);
}